// Round 1
// baseline (490.033 us; speedup 1.0000x reference)
//
#include <hip/hip_runtime.h>

#define A_DIM 6
#define HID_D 64
#define LATENT_D 64
#define GRU_IN_D 134
#define T_STEPS 128
#define N_ENV 10
#define BN_TOT 640

typedef float f2 __attribute__((ext_vector_type(2)));

__device__ __forceinline__ float fast_sigmoid(float x) {
    return __builtin_amdgcn_rcpf(1.0f + __builtin_amdgcn_exp2f(-1.4426950408889634f * x));
}
__device__ __forceinline__ float fast_tanh(float x) {
    return 1.0f - 2.0f * __builtin_amdgcn_rcpf(1.0f + __builtin_amdgcn_exp2f(2.8853900817779268f * x));
}

template<int CTRL>
__device__ __forceinline__ float dppadd(float v) {
    int t = __builtin_amdgcn_update_dpp(0, __builtin_bit_cast(int, v), CTRL, 0xf, 0xf, true);
    return v + __builtin_bit_cast(float, t);
}
// sum over all 64 lanes -> wave-uniform scalar (VALU pipe only)
__device__ __forceinline__ float wave_reduce_add(float v) {
    v = dppadd<0x111>(v);   // row_shr:1
    v = dppadd<0x112>(v);   // row_shr:2
    v = dppadd<0x114>(v);   // row_shr:4
    v = dppadd<0x118>(v);   // row_shr:8
    v = dppadd<0x142>(v);   // row_bcast:15
    v = dppadd<0x143>(v);   // row_bcast:31 -> lane 63 has total
    return __builtin_bit_cast(float, __builtin_amdgcn_readlane(__builtin_bit_cast(int, v), 63));
}

__global__ __launch_bounds__(128, 1)
void policy_kernel(const float* __restrict__ s_h,
                   const int*   __restrict__ a_h,
                   const float* __restrict__ b_z,
                   const float* __restrict__ conv1_w, const float* __restrict__ conv1_b,
                   const float* __restrict__ conv2_w, const float* __restrict__ conv2_b,
                   const float* __restrict__ fc_w,    const float* __restrict__ fc_b,
                   const float* __restrict__ emb,
                   const float* __restrict__ gru_wih, const float* __restrict__ gru_whh,
                   const float* __restrict__ gru_bih, const float* __restrict__ gru_bhh,
                   const float* __restrict__ mlp1_w,  const float* __restrict__ mlp1_b,
                   const float* __restrict__ mlp2_w,  const float* __restrict__ mlp2_b,
                   float* __restrict__ logits_out, float* __restrict__ mask_out)
{
    __shared__ __align__(16) float s0[512];      // frame0 [c][h][w]
    __shared__ __align__(16) float a1[1152];     // conv1 out [32][36]
    __shared__ __align__(16) float a2[512];      // conv2 out flat
    __shared__ __align__(16) float pfc[128];     // fc partials
    __shared__ __align__(16) float semb[64];
    __shared__ __align__(16) float gxc[192];     // step-invariant gx (+biases)
    __shared__ __align__(16) float atab[6*192];  // per-action gx contribution
    __shared__ __align__(16) float hspec[6*64];  // speculative h_{t+1} per action
    // Transposed-paired weights in LDS (conflict-free b64 reads):
    //   lwn2[k2*64 + j] = { Whh_n[j][2k2], Whh_n[j][2k2+1] }   (rows 128..191 of gru_whh)
    //   lw12[k2*64 + j] = { mlp1_w[j][2k2], mlp1_w[j][2k2+1] }
    __shared__ f2 lwn2[2048];
    __shared__ f2 lw12[2048];

    const int bn  = blockIdx.x;          // 0..639
    const int tid = threadIdx.x;         // 0..127 (preamble); rollout = wave 0 only
    const int j   = tid & 63;
    const int w   = tid >> 6;

    // ---- masks output ----
    mask_out[bn * T_STEPS + tid] = (a_h[bn * T_STEPS + tid] != (A_DIM - 1)) ? 1.0f : 0.0f;

    // ---- load frame 0 ----
    {
        const float* src = s_h + (size_t)bn * T_STEPS * 512;
        #pragma unroll
        for (int i = 0; i < 4; ++i) s0[tid + i * 128] = src[tid + i * 128];
    }

    // ---- stage wn / w1 into LDS (transposed f2 pairs) ----
    for (int i2 = tid; i2 < 2048; i2 += 128) {
        const int k2 = i2 >> 6, jj = i2 & 63;
        lwn2[i2] = *(const f2*)&gru_whh[(128 + jj) * 64 + 2 * k2];
        lw12[i2] = *(const f2*)&mlp1_w[(size_t)jj * 64 + 2 * k2];
    }
    __syncthreads();

    // ---- conv1: (8,8,8) -> (32,6,6), ReLU ----
    for (int i = tid; i < 1152; i += 128) {
        const int oc = i / 36, r = i % 36, oh = r / 6, ow = r % 6;
        float sum = conv1_b[oc];
        const float* wp = conv1_w + oc * 72;
        #pragma unroll
        for (int ic = 0; ic < 8; ++ic)
            #pragma unroll
            for (int kh = 0; kh < 3; ++kh)
                #pragma unroll
                for (int kw = 0; kw < 3; ++kw)
                    sum = fmaf(s0[ic * 64 + (oh + kh) * 8 + (ow + kw)],
                               wp[ic * 9 + kh * 3 + kw], sum);
        a1[i] = fmaxf(sum, 0.0f);
    }
    __syncthreads();

    // ---- conv2: (32,6,6) -> (32,4,4), ReLU ----
    for (int i = tid; i < 512; i += 128) {
        const int oc = i / 16, r = i % 16, oh = r / 4, ow = r % 4;
        float sum = conv2_b[oc];
        const float* wp = conv2_w + oc * 288;
        for (int ic = 0; ic < 32; ++ic)
            #pragma unroll
            for (int kh = 0; kh < 3; ++kh)
                #pragma unroll
                for (int kw = 0; kw < 3; ++kw)
                    sum = fmaf(a1[ic * 36 + (oh + kh) * 6 + (ow + kw)],
                               wp[ic * 9 + kh * 3 + kw], sum);
        a2[i] = fmaxf(sum, 0.0f);
    }
    __syncthreads();

    // ---- fc: 512 -> 64, ReLU (k-split across 2 waves) ----
    {
        const float* wp = fc_w + j * 512 + w * 256;
        const float* ap = a2 + w * 256;
        float s0a = 0.f, s1a = 0.f, s2a = 0.f, s3a = 0.f;
        for (int k = 0; k < 256; k += 4) {
            s0a = fmaf(ap[k + 0], wp[k + 0], s0a);
            s1a = fmaf(ap[k + 1], wp[k + 1], s1a);
            s2a = fmaf(ap[k + 2], wp[k + 2], s2a);
            s3a = fmaf(ap[k + 3], wp[k + 3], s3a);
        }
        pfc[tid] = (s0a + s1a) + (s2a + s3a);
    }
    __syncthreads();
    if (tid < 64) semb[tid] = fmaxf(pfc[tid] + pfc[tid + 64] + fc_b[tid], 0.0f);
    __syncthreads();

    // ---- step-invariant gx ----
    {
        const float* bz = b_z + (size_t)(bn / N_ENV) * LATENT_D;
        for (int g = tid; g < 192; g += 128) {
            float sum = gru_bih[g] + ((g < 128) ? gru_bhh[g] : 0.0f);
            const float* wp = gru_wih + g * GRU_IN_D;
            for (int k = 0; k < 64; ++k) sum = fmaf(semb[k], wp[k], sum);
            for (int k = 0; k < 64; ++k) sum = fmaf(bz[k], wp[70 + k], sum);
            gxc[g] = sum;
        }
    }
    // ---- action table ----
    for (int i = tid; i < 6 * 192; i += 128) {
        const int a = i / 192, g = i % 192;
        float sum = 0.0f;
        #pragma unroll
        for (int q = 0; q < 6; ++q)
            sum = fmaf(emb[a * 6 + q], gru_wih[g * GRU_IN_D + 64 + q], sum);
        atab[i] = sum;
    }
    __syncthreads();

    if (w == 1) return;   // rollout is single-wave; wave 1 exits

    // ---- per-lane fp32 weights: ONLY wr, wz stay in VGPRs (128 regs).
    //      wn, w1 are served from LDS (lwn2/lw12) each step -> no spills.
    f2 wr[32], wz[32];
    {
        const float* pr = gru_whh + (size_t)j * 64;
        const float* pz = gru_whh + (size_t)(64 + j) * 64;
        #pragma unroll
        for (int i = 0; i < 16; ++i) {
            float4 v;
            v = ((const float4*)pr)[i]; wr[2*i] = (f2){v.x, v.y}; wr[2*i+1] = (f2){v.z, v.w};
            v = ((const float4*)pz)[i]; wz[2*i] = (f2){v.x, v.y}; wz[2*i+1] = (f2){v.z, v.w};
        }
    }
    const float bhn = gru_bhh[128 + j];
    const float b1j = mlp1_b[j];
    // step-invariant per-action gate inputs: arx[a] = gx_r + atab_r[a], etc.
    float arx[6], azx[6], anx[6], m2c[6], b2[6];
    {
        const float gxr = gxc[j], gxz = gxc[64 + j], gxn = gxc[128 + j];
        #pragma unroll
        for (int a = 0; a < 6; ++a) {
            arx[a] = gxr + atab[a * 192 + j];
            azx[a] = gxz + atab[a * 192 + 64 + j];
            anx[a] = gxn + atab[a * 192 + 128 + j];
            m2c[a] = mlp2_w[a * 64 + j];
            b2[a] = mlp2_b[a];
        }
    }

    // per-lane LDS bases for the transposed weight reads (lane j's column)
    const f2* __restrict__ wnj = lwn2 + j;   // index k2*64
    const f2* __restrict__ w1j = lw12 + j;

    // ---- seed: speculative h_1 candidates from h_0 = 0 ----
    // dots(h_0): hr = hz = 0, hn = bhn
    float ha[6];
    #pragma unroll
    for (int a = 0; a < 6; ++a) {
        const float r = fast_sigmoid(arx[a]);
        const float z = fast_sigmoid(azx[a]);
        const float n = fast_tanh(fmaf(r, bhn, anx[a]));
        ha[a] = fmaf(z, 0.0f - n, n);            // (1-z)*n + z*0
    }
    __builtin_amdgcn_wave_barrier();
    #pragma unroll
    for (int a = 0; a < 6; ++a) hspec[a * 64 + j] = ha[a];
    __builtin_amdgcn_wave_barrier();

    int act = A_DIM - 1;
    float* lout = logits_out + (size_t)bn * (T_STEPS - 1) * A_DIM;

    for (int t = 0; t < T_STEPS - 1; ++t) {
        // critical path: act -> address -> sweep of h_{t+1} = hspec[act]
        const float4* hb = (const float4*)(hspec + (act << 6));
        // h_{t+1}[j] for this lane (for next speculative gates; off critical path)
        float hprev = ha[0];
        #pragma unroll
        for (int a = 1; a < 6; ++a) hprev = (act == a) ? ha[a] : hprev;

        // fused sweep: mlp1 + r/z/n dots. wr/wz from regs, wn/w1 from LDS.
        // Two accumulator chains each (A=even k2, B=odd k2) -> dep chain 16.
        f2 p1a = {0.f, 0.f}, p1b = {0.f, 0.f};
        f2 pra = {0.f, 0.f}, prb = {0.f, 0.f};
        f2 pza = {0.f, 0.f}, pzb = {0.f, 0.f};
        f2 pna = {0.f, 0.f}, pnb = {0.f, 0.f};
        #pragma unroll
        for (int i = 0; i < 16; ++i) {
            const float4 hv = hb[i];
            const f2 hA = (f2){hv.x, hv.y};
            const f2 hB = (f2){hv.z, hv.w};
            pra += hA * wr[2*i];          prb += hB * wr[2*i+1];
            pza += hA * wz[2*i];          pzb += hB * wz[2*i+1];
            pna += hA * wnj[(2*i) * 64];  pnb += hB * wnj[(2*i+1) * 64];
            p1a += hA * w1j[(2*i) * 64];  p1b += hB * w1j[(2*i+1) * 64];
        }
        const f2 p1 = p1a + p1b;
        const float hid = fast_tanh(p1.x + p1.y + b1j);
        const f2 prf = pra + prb;
        const f2 pzf = pza + pzb;
        const f2 pnf = pna + pnb;
        const float hr = prf.x + prf.y;
        const float hz = pzf.x + pzf.y;
        const float hn = pnf.x + pnf.y + bhn;

        // mlp2 via DPP wave reduction (critical path: hid -> l -> argmax)
        const float l0 = wave_reduce_add(hid * m2c[0]) + b2[0];
        const float l1 = wave_reduce_add(hid * m2c[1]) + b2[1];
        const float l2 = wave_reduce_add(hid * m2c[2]) + b2[2];
        const float l3 = wave_reduce_add(hid * m2c[3]) + b2[3];
        const float l4 = wave_reduce_add(hid * m2c[4]) + b2[4];
        const float l5 = wave_reduce_add(hid * m2c[5]) + b2[5];

        // speculative gates for ALL 6 actions (independent of argmax; fills
        // the DPP latency window). Produces candidate h_{t+2} values.
        #pragma unroll
        for (int a = 0; a < 6; ++a) {
            const float r = fast_sigmoid(arx[a] + hr);
            const float z = fast_sigmoid(azx[a] + hz);
            const float n = fast_tanh(fmaf(r, hn, anx[a]));
            ha[a] = fmaf(z, hprev - n, n);
        }
        __builtin_amdgcn_wave_barrier();
        #pragma unroll
        for (int a = 0; a < 6; ++a) hspec[a * 64 + j] = ha[a];
        __builtin_amdgcn_wave_barrier();

        // argmax, first-max-wins
        float best = l0; int bi = 0;
        if (l1 > best) { best = l1; bi = 1; }
        if (l2 > best) { best = l2; bi = 2; }
        if (l3 > best) { best = l3; bi = 3; }
        if (l4 > best) { best = l4; bi = 4; }
        if (l5 > best) { best = l5; bi = 5; }
        act = bi;

        if (j < A_DIM) {
            const float outv = (j == 0) ? l0 : (j == 1) ? l1 : (j == 2) ? l2
                             : (j == 3) ? l3 : (j == 4) ? l4 : l5;
            lout[t * A_DIM + j] = outv;
        }
    }
}

extern "C" void kernel_launch(void* const* d_in, const int* in_sizes, int n_in,
                              void* d_out, int out_size, void* d_ws, size_t ws_size,
                              hipStream_t stream) {
    const float* s_h     = (const float*)d_in[0];
    const int*   a_h     = (const int*)  d_in[1];
    const float* b_z     = (const float*)d_in[2];
    const float* conv1_w = (const float*)d_in[3];
    const float* conv1_b = (const float*)d_in[4];
    const float* conv2_w = (const float*)d_in[5];
    const float* conv2_b = (const float*)d_in[6];
    const float* fc_w    = (const float*)d_in[7];
    const float* fc_b    = (const float*)d_in[8];
    const float* emb     = (const float*)d_in[9];
    const float* gru_wih = (const float*)d_in[10];
    const float* gru_whh = (const float*)d_in[11];
    const float* gru_bih = (const float*)d_in[12];
    const float* gru_bhh = (const float*)d_in[13];
    const float* mlp1_w  = (const float*)d_in[14];
    const float* mlp1_b  = (const float*)d_in[15];
    const float* mlp2_w  = (const float*)d_in[16];
    const float* mlp2_b  = (const float*)d_in[17];

    float* out = (float*)d_out;
    float* logits_out = out;                                          // (B,N,127,6)
    float* mask_out   = out + (size_t)BN_TOT * (T_STEPS - 1) * A_DIM; // (B,N,128,1)

    policy_kernel<<<BN_TOT, 128, 0, stream>>>(
        s_h, a_h, b_z, conv1_w, conv1_b, conv2_w, conv2_b, fc_w, fc_b, emb,
        gru_wih, gru_whh, gru_bih, gru_bhh, mlp1_w, mlp1_b, mlp2_w, mlp2_b,
        logits_out, mask_out);
}